// Round 4
// baseline (162.791 us; speedup 1.0000x reference)
//
#include <hip/hip_runtime.h>

// PercolationQ: per-patch occupancy fraction -> threshold -> mean over patches.
// Every (color,batch) row is 65536 floats = 16384 float4 = 64 KB for ALL box
// sizes -> one block (512 thr) per row, 576 blocks, perfectly balanced.
// Coalesced dwordx4, 8 loads in flight before any consumption, shuffle trees
// after. Patch alignment per wave-instruction (64 consecutive float4):
//   x4 : patch = 4 lanes   (xor 1,2)
//   x8 : patch = 16 lanes  (xor 1,2,4,8)
//   x16: patch = whole instruction (xor 1..32)
// cnt is accumulated via ballot+popc -> WAVE-UNIFORM; lane 0 writes it
// directly (R3 bug: an extra 64-lane shfl reduction multiplied it by 64).
// One block per output element -> plain store, NO atomics, NO memset dispatch.
// out: 576 floats = [q4(192) | q8(192) | q16(192)], row-major [c*64+b].

#define PERC_THRESHOLD 0.59275f

__global__ __launch_bounds__(512)
void PercolationQ_31885837205970_kernel(const float* __restrict__ x4,
                                        const float* __restrict__ x8,
                                        const float* __restrict__ x16,
                                        float* __restrict__ out) {
    const int r = blockIdx.x;      // 0..575
    const int t = threadIdx.x;     // 0..511
    const int lane = t & 63;

    const float4* __restrict__ src;
    int type;
    float invB2;          // 1/B^2 (pow2 -> exact), compare s*invB2 >= THR
    float* o;
    float invP;

    if (r < 192) {                 // x16 rows first
        src = (const float4*)x16 + (size_t)r * 16384;
        type = 2; invB2 = 1.0f / 256.0f; o = out + 384 + r; invP = 1.0f / 256.0f;
    } else if (r < 384) {          // x8
        int b = r - 192;
        src = (const float4*)x8 + (size_t)b * 16384;
        type = 1; invB2 = 1.0f / 64.0f; o = out + 192 + b; invP = 1.0f / 1024.0f;
    } else {                       // x4
        int b = r - 384;
        src = (const float4*)x4 + (size_t)b * 16384;
        type = 0; invB2 = 1.0f / 16.0f; o = out + b; invP = 1.0f / 4096.0f;
    }

    int cnt = 0;   // accumulated via ballot/popc -> wave-uniform
    // 32 coalesced dwordx4 per thread, in batches of 8 kept in flight together
#pragma unroll
    for (int base = 0; base < 32; base += 8) {
        float4 v[8];
#pragma unroll
        for (int k = 0; k < 8; ++k)
            v[k] = src[(size_t)(base + k) * 512 + t];

        float s[8];
#pragma unroll
        for (int k = 0; k < 8; ++k)
            s[k] = (v[k].x + v[k].y) + (v[k].z + v[k].w);

        if (type == 0) {           // patch = 4 lanes
#pragma unroll
            for (int k = 0; k < 8; ++k) {
                float a = s[k] + __shfl_xor(s[k], 1, 64);
                a += __shfl_xor(a, 2, 64);
                bool p = ((lane & 3) == 0) && (a * invB2 >= PERC_THRESHOLD);
                cnt += __popcll(__ballot(p));
            }
        } else if (type == 1) {    // patch = 16 lanes
#pragma unroll
            for (int k = 0; k < 8; ++k) {
                float a = s[k] + __shfl_xor(s[k], 1, 64);
                a += __shfl_xor(a, 2, 64);
                a += __shfl_xor(a, 4, 64);
                a += __shfl_xor(a, 8, 64);
                bool p = ((lane & 15) == 0) && (a * invB2 >= PERC_THRESHOLD);
                cnt += __popcll(__ballot(p));
            }
        } else {                   // patch = whole wave-instruction
#pragma unroll
            for (int k = 0; k < 8; ++k) {
                float a = s[k] + __shfl_xor(s[k], 1, 64);
                a += __shfl_xor(a, 2, 64);
                a += __shfl_xor(a, 4, 64);
                a += __shfl_xor(a, 8, 64);
                a += __shfl_xor(a, 16, 64);
                a += __shfl_xor(a, 32, 64);
                bool p = (lane == 0) && (a * invB2 >= PERC_THRESHOLD);
                cnt += __popcll(__ballot(p));
            }
        }
    }

    // cnt is wave-uniform: lane 0 of each wave writes it, thread 0 sums waves
    __shared__ int wsum[8];
    if (lane == 0) wsum[t >> 6] = cnt;
    __syncthreads();
    if (t == 0) {
        int total = 0;
#pragma unroll
        for (int w = 0; w < 8; ++w) total += wsum[w];
        *o = (float)total * invP;   // invP = 2^-k -> exact
    }
}

extern "C" void kernel_launch(void* const* d_in, const int* in_sizes, int n_in,
                              void* d_out, int out_size, void* d_ws, size_t ws_size,
                              hipStream_t stream) {
    const float* x4  = (const float*)d_in[0];
    const float* x8  = (const float*)d_in[1];
    const float* x16 = (const float*)d_in[2];
    float* out = (float*)d_out;

    // every output element is written exactly once by its block -> no memset
    dim3 grid(576), block(512);
    hipLaunchKernelGGL(PercolationQ_31885837205970_kernel, grid, block, 0, stream,
                       x4, x8, x16, out);
}